// Round 1
// baseline (98.666 us; speedup 1.0000x reference)
//
#include <hip/hip_runtime.h>

#define NNX 64
#define NNY 64
#define NNZ 64
#define NQ 200
#define BATCH 2

__device__ __forceinline__ constexpr float DXF() { return 1.0f / 63.0f; }

__global__ void interface_boundary_loss_kernel(
    const float* __restrict__ output,   // (BATCH, 1, 64, 64, 64)
    const float* __restrict__ q,        // (NQ,)
    const float* __restrict__ xq,       // (NQ, 3)
    const int*   __restrict__ x_idx,    // (Nb,)
    const int*   __restrict__ y_idx,
    const int*   __restrict__ z_idx,
    const float* __restrict__ normals,  // (Nb, 3)
    float*       __restrict__ out,      // scalar
    int nb)
{
    constexpr float EPS     = 1.1920929e-07f;   // np.finfo(float32).eps
    constexpr float FOUR_PI = 12.566370614359172f;
    constexpr float E_IN    = 1.0f;
    constexpr float E_OUT   = 80.0f;
    constexpr float INV_DX  = 63.0f;            // 1/DX exactly

    __shared__ float s_q[NQ];
    __shared__ float s_xq[NQ * 3];
    for (int t = threadIdx.x; t < NQ; t += blockDim.x)     s_q[t]  = q[t];
    for (int t = threadIdx.x; t < NQ * 3; t += blockDim.x) s_xq[t] = xq[t];
    __syncthreads();

    const int i = blockIdx.x * blockDim.x + threadIdx.x;
    float contrib = 0.0f;

    if (i < nb) {
        const int xi = x_idx[i], yi = y_idx[i], zi = z_idx[i];
        const float px = xi * DXF();
        const float py = yi * DXF();
        const float pz = zi * DXF();

        // Green's function and gradient at this boundary point
        float g = 0.0f, gx = 0.0f, gy = 0.0f, gz = 0.0f;
        for (int j = 0; j < NQ; ++j) {
            const float dx = px - s_xq[3 * j + 0];
            const float dy = py - s_xq[3 * j + 1];
            const float dz = pz - s_xq[3 * j + 2];
            const float r2 = dx * dx + dy * dy + dz * dz;
            const float r  = sqrtf(r2);
            const float rr = (r == 0.0f) ? EPS : r;
            const float qj = s_q[j];
            g += qj / rr;
            const float r3  = r2 * r;                 // r2^1.5
            const float rr3 = (r3 == 0.0f) ? EPS : r3;
            const float coef = -qj / rr3;
            gx += coef * dx;
            gy += coef * dy;
            gz += coef * dz;
        }
        const float inv4pi = 1.0f / (E_IN * FOUR_PI);
        g  *= inv4pi;
        gx *= inv4pi;
        gy *= inv4pi;
        gz *= inv4pi;

        const float nx = normals[3 * i + 0];
        const float ny = normals[3 * i + 1];
        const float nz = normals[3 * i + 2];
        const float gc_nd = gx * nx + gy * ny + gz * nz;

        // finite-difference normal derivatives, per batch
        const int base = (xi * NNY + yi) * NNZ + zi;
        float t2sum = 0.0f;
#pragma unroll
        for (int b = 0; b < BATCH; ++b) {
            const float* o = output + (size_t)b * (NNX * NNY * NNZ);
            const float c     = o[base];
            const float left  = o[base - NNY * NNZ];
            const float right = o[base + NNY * NNZ];
            const float below = o[base - NNZ];
            const float above = o[base + NNZ];
            const float back  = o[base - 1];
            const float front = o[base + 1];

            const float gx_in  = (nx > 0.0f) ? (c - left)  : (right - c);
            const float gx_out = (nx > 0.0f) ? (right - c) : (c - left);
            const float gy_in  = (ny > 0.0f) ? (c - below) : (above - c);
            const float gy_out = (ny > 0.0f) ? (above - c) : (c - below);
            const float gz_in  = (nz > 0.0f) ? (c - back)  : (front - c);
            const float gz_out = (nz > 0.0f) ? (front - c) : (c - back);

            const float nd_in  = (gx_in  * nx + gy_in  * ny + gz_in  * nz) * INV_DX;
            const float nd_out = (gx_out * nx + gy_out * ny + gz_out * nz) * INV_DX;

            const float t = E_IN * (nd_in + gc_nd) - E_OUT * nd_out;
            t2sum += t * t;
        }

        // loss_i = (Σ_b g² + Σ_b t²) / (BATCH * Nb);  Σ_b g² = BATCH·g²
        contrib = ((float)BATCH * g * g + t2sum) / ((float)BATCH * (float)nb);
    }

    // block reduction: wave64 shuffle, then LDS across waves
    float v = contrib;
    for (int off = 32; off > 0; off >>= 1)
        v += __shfl_down(v, off, 64);

    __shared__ float s_wave[4];   // 256 threads = 4 waves
    const int lane = threadIdx.x & 63;
    const int wave = threadIdx.x >> 6;
    if (lane == 0) s_wave[wave] = v;
    __syncthreads();
    if (threadIdx.x == 0) {
        float bsum = s_wave[0] + s_wave[1] + s_wave[2] + s_wave[3];
        atomicAdd(out, bsum);
    }
}

extern "C" void kernel_launch(void* const* d_in, const int* in_sizes, int n_in,
                              void* d_out, int out_size, void* d_ws, size_t ws_size,
                              hipStream_t stream) {
    const float* output  = (const float*)d_in[0];
    const float* q       = (const float*)d_in[1];
    const float* xq      = (const float*)d_in[2];
    // d_in[3] = points — redundant, reconstructed from indices
    const int*   x_idx   = (const int*)d_in[4];
    const int*   y_idx   = (const int*)d_in[5];
    const int*   z_idx   = (const int*)d_in[6];
    const float* normals = (const float*)d_in[7];
    float* out = (float*)d_out;

    const int nb = in_sizes[4];

    hipMemsetAsync(out, 0, sizeof(float), stream);

    const int block = 256;
    const int grid  = (nb + block - 1) / block;
    interface_boundary_loss_kernel<<<grid, block, 0, stream>>>(
        output, q, xq, x_idx, y_idx, z_idx, normals, out, nb);
}

// Round 2
// 74.480 us; speedup vs baseline: 1.3247x; 1.3247x over previous
//
#include <hip/hip_runtime.h>

#define NNX 64
#define NNY 64
#define NNZ 64
#define NQ 200
#define BATCH 2
#define PT 64          // points per block
#define NC 4           // charge chunks (waves) per block
#define CH (NQ / NC)   // charges per chunk = 50

__global__ void __launch_bounds__(256)
interface_boundary_loss_kernel(
    const float* __restrict__ output,   // (BATCH, 1, 64, 64, 64)
    const float* __restrict__ q,        // (NQ,)
    const float* __restrict__ xq,       // (NQ, 3)
    const int*   __restrict__ x_idx,    // (Nb,)
    const int*   __restrict__ y_idx,
    const int*   __restrict__ z_idx,
    const float* __restrict__ normals,  // (Nb, 3)
    float*       __restrict__ out,      // scalar (pre-zeroed)
    int nb)
{
    constexpr float INV_EPS = 8388608.0f;         // 1 / np.float32 eps = 2^23
    constexpr float FOUR_PI = 12.566370614359172f;
    constexpr float E_IN    = 1.0f;
    constexpr float E_OUT   = 80.0f;
    constexpr float INV_DX  = 63.0f;
    constexpr float DXF     = 1.0f / 63.0f;

    __shared__ float4 s_pk[NQ];                   // (xq.x, xq.y, xq.z, q)
    __shared__ float  s_red[4][NC][PT];           // [qty][chunk][lane]

    // stage charges: one float4 per charge
    for (int t = threadIdx.x; t < NQ; t += blockDim.x) {
        s_pk[t] = make_float4(xq[3 * t + 0], xq[3 * t + 1], xq[3 * t + 2], q[t]);
    }
    __syncthreads();

    const int lane  = threadIdx.x & 63;
    const int chunk = threadIdx.x >> 6;           // 0..3
    const int p     = blockIdx.x * PT + lane;

    float g = 0.0f, gx = 0.0f, gy = 0.0f, gz = 0.0f;

    if (p < nb) {
        const float px = x_idx[p] * DXF;
        const float py = y_idx[p] * DXF;
        const float pz = z_idx[p] * DXF;

#pragma unroll 10
        for (int j = chunk * CH; j < (chunk + 1) * CH; ++j) {
            const float4 pk = s_pk[j];            // broadcast ds_read_b128
            const float dx = px - pk.x;
            const float dy = py - pk.y;
            const float dz = pz - pk.z;
            const float r2 = dx * dx + dy * dy + dz * dz;
            const float rsq = __builtin_amdgcn_rsqf(r2);     // inf if r2==0
            const bool  zero = (r2 == 0.0f);
            const float inv_r  = zero ? INV_EPS : rsq;
            const float inv_r3 = zero ? INV_EPS : rsq * rsq * rsq;
            const float qj = pk.w;
            g += qj * inv_r;
            const float coef = -qj * inv_r3;
            gx += coef * dx;
            gy += coef * dy;
            gz += coef * dz;
        }
    }

    s_red[0][chunk][lane] = g;
    s_red[1][chunk][lane] = gx;
    s_red[2][chunk][lane] = gy;
    s_red[3][chunk][lane] = gz;
    __syncthreads();

    float contrib = 0.0f;

    if (chunk == 0) {                             // wave 0 finishes its 64 points
        if (p < nb) {
            const float inv4pi = 1.0f / (E_IN * FOUR_PI);
            float sg  = (s_red[0][0][lane] + s_red[0][1][lane]) +
                        (s_red[0][2][lane] + s_red[0][3][lane]);
            float sgx = (s_red[1][0][lane] + s_red[1][1][lane]) +
                        (s_red[1][2][lane] + s_red[1][3][lane]);
            float sgy = (s_red[2][0][lane] + s_red[2][1][lane]) +
                        (s_red[2][2][lane] + s_red[2][3][lane]);
            float sgz = (s_red[3][0][lane] + s_red[3][1][lane]) +
                        (s_red[3][2][lane] + s_red[3][3][lane]);
            sg *= inv4pi; sgx *= inv4pi; sgy *= inv4pi; sgz *= inv4pi;

            const float nx = normals[3 * p + 0];
            const float ny = normals[3 * p + 1];
            const float nz = normals[3 * p + 2];
            const float gc_nd = sgx * nx + sgy * ny + sgz * nz;

            const int xi = x_idx[p], yi = y_idx[p], zi = z_idx[p];
            const int base = (xi * NNY + yi) * NNZ + zi;
            float t2sum = 0.0f;
#pragma unroll
            for (int b = 0; b < BATCH; ++b) {
                const float* o = output + (size_t)b * (NNX * NNY * NNZ);
                const float c     = o[base];
                const float left  = o[base - NNY * NNZ];
                const float right = o[base + NNY * NNZ];
                const float below = o[base - NNZ];
                const float above = o[base + NNZ];
                const float back  = o[base - 1];
                const float front = o[base + 1];

                const float gx_in  = (nx > 0.0f) ? (c - left)  : (right - c);
                const float gx_out = (nx > 0.0f) ? (right - c) : (c - left);
                const float gy_in  = (ny > 0.0f) ? (c - below) : (above - c);
                const float gy_out = (ny > 0.0f) ? (above - c) : (c - below);
                const float gz_in  = (nz > 0.0f) ? (c - back)  : (front - c);
                const float gz_out = (nz > 0.0f) ? (front - c) : (c - back);

                const float nd_in  = (gx_in  * nx + gy_in  * ny + gz_in  * nz) * INV_DX;
                const float nd_out = (gx_out * nx + gy_out * ny + gz_out * nz) * INV_DX;

                const float t = E_IN * (nd_in + gc_nd) - E_OUT * nd_out;
                t2sum += t * t;
            }
            // per-point: B*g^2 + sum_b t^2 ; global scale 1/(B*nb) applied at atomic
            contrib = (float)BATCH * sg * sg + t2sum;
        }

        // wave-64 reduction of contrib
        float v = contrib;
        for (int off = 32; off > 0; off >>= 1)
            v += __shfl_down(v, off, 64);
        if (lane == 0) {
            const float scale = 1.0f / ((float)BATCH * (float)nb);
            atomicAdd(out, v * scale);
        }
    }
}

extern "C" void kernel_launch(void* const* d_in, const int* in_sizes, int n_in,
                              void* d_out, int out_size, void* d_ws, size_t ws_size,
                              hipStream_t stream) {
    const float* output  = (const float*)d_in[0];
    const float* q       = (const float*)d_in[1];
    const float* xq      = (const float*)d_in[2];
    // d_in[3] = points — redundant, reconstructed from indices
    const int*   x_idx   = (const int*)d_in[4];
    const int*   y_idx   = (const int*)d_in[5];
    const int*   z_idx   = (const int*)d_in[6];
    const float* normals = (const float*)d_in[7];
    float* out = (float*)d_out;

    const int nb = in_sizes[4];

    hipMemsetAsync(out, 0, sizeof(float), stream);

    const int block = 256;                 // 64 points x 4 charge-chunks
    const int grid  = (nb + PT - 1) / PT;
    interface_boundary_loss_kernel<<<grid, block, 0, stream>>>(
        output, q, xq, x_idx, y_idx, z_idx, normals, out, nb);
}

// Round 3
// 72.846 us; speedup vs baseline: 1.3545x; 1.0224x over previous
//
#include <hip/hip_runtime.h>

#define NNX 64
#define NNY 64
#define NNZ 64
#define NQ 200
#define BATCH 2
#define PT 32          // points per block
#define NC 8           // charge chunks per block (half-waves)
#define CH (NQ / NC)   // charges per chunk = 25

__global__ void __launch_bounds__(256)
interface_boundary_loss_kernel(
    const float* __restrict__ output,   // (BATCH, 1, 64, 64, 64)
    const float* __restrict__ q,        // (NQ,)
    const float* __restrict__ xq,       // (NQ, 3)
    const int*   __restrict__ x_idx,    // (Nb,)
    const int*   __restrict__ y_idx,
    const int*   __restrict__ z_idx,
    const float* __restrict__ normals,  // (Nb, 3)
    float*       __restrict__ out,      // scalar (pre-zeroed)
    int nb)
{
    constexpr float INV_EPS = 8388608.0f;         // 1 / np.float32 eps = 2^23
    constexpr float FOUR_PI = 12.566370614359172f;
    constexpr float E_IN    = 1.0f;
    constexpr float E_OUT   = 80.0f;
    constexpr float INV_DX  = 63.0f;
    constexpr float DXF     = 1.0f / 63.0f;

    __shared__ float4 s_pk[NQ];                   // (xq.x, xq.y, xq.z, q)
    __shared__ float  s_red[4][NC][PT];           // [qty][chunk][lane] = 4 KB

    // stage charges: one float4 per charge (one round: 200 < 256)
    {
        const int t = threadIdx.x;
        if (t < NQ) {
            s_pk[t] = make_float4(xq[3 * t + 0], xq[3 * t + 1], xq[3 * t + 2], q[t]);
        }
    }

    const int lane  = threadIdx.x & 31;           // point within block
    const int chunk = threadIdx.x >> 5;           // 0..7 charge chunk
    const int p     = blockIdx.x * PT + lane;
    const bool live = (p < nb);

    // issue per-point index loads early (needed by all chunks)
    int xi = 0, yi = 0, zi = 0;
    if (live) { xi = x_idx[p]; yi = y_idx[p]; zi = z_idx[p]; }
    const float px = xi * DXF, py = yi * DXF, pz = zi * DXF;

    // chunk 0 additionally prefetches normals + the 14 FD gathers so their
    // latency overlaps the charge loop
    float nx = 0.f, ny = 0.f, nz = 0.f;
    float fd[BATCH][7];
    if (chunk == 0 && live) {
        nx = normals[3 * p + 0];
        ny = normals[3 * p + 1];
        nz = normals[3 * p + 2];
        const int base = (xi * NNY + yi) * NNZ + zi;
#pragma unroll
        for (int b = 0; b < BATCH; ++b) {
            const float* o = output + (size_t)b * (NNX * NNY * NNZ);
            fd[b][0] = o[base];
            fd[b][1] = o[base - NNY * NNZ];
            fd[b][2] = o[base + NNY * NNZ];
            fd[b][3] = o[base - NNZ];
            fd[b][4] = o[base + NNZ];
            fd[b][5] = o[base - 1];
            fd[b][6] = o[base + 1];
        }
    }

    __syncthreads();   // charges staged

    float g = 0.0f, gx = 0.0f, gy = 0.0f, gz = 0.0f;
    if (live) {
        const int j0 = chunk * CH;
#pragma unroll 5
        for (int jj = 0; jj < CH; ++jj) {
            const float4 pk = s_pk[j0 + jj];
            const float dx = px - pk.x;
            const float dy = py - pk.y;
            const float dz = pz - pk.z;
            const float r2 = dx * dx + dy * dy + dz * dz;
            const float rsq = __builtin_amdgcn_rsqf(r2);     // inf if r2==0
            const bool  zero = (r2 == 0.0f);
            const float inv_r  = zero ? INV_EPS : rsq;
            const float inv_r3 = zero ? INV_EPS : rsq * rsq * rsq;
            const float qj = pk.w;
            g += qj * inv_r;
            const float coef = -qj * inv_r3;
            gx += coef * dx;
            gy += coef * dy;
            gz += coef * dz;
        }
    }

    s_red[0][chunk][lane] = g;
    s_red[1][chunk][lane] = gx;
    s_red[2][chunk][lane] = gy;
    s_red[3][chunk][lane] = gz;
    __syncthreads();

    float contrib = 0.0f;

    if (chunk == 0 && live) {
        const float inv4pi = 1.0f / (E_IN * FOUR_PI);
        float sg = 0.f, sgx = 0.f, sgy = 0.f, sgz = 0.f;
#pragma unroll
        for (int c = 0; c < NC; ++c) {
            sg  += s_red[0][c][lane];
            sgx += s_red[1][c][lane];
            sgy += s_red[2][c][lane];
            sgz += s_red[3][c][lane];
        }
        sg *= inv4pi; sgx *= inv4pi; sgy *= inv4pi; sgz *= inv4pi;

        const float gc_nd = sgx * nx + sgy * ny + sgz * nz;

        float t2sum = 0.0f;
#pragma unroll
        for (int b = 0; b < BATCH; ++b) {
            const float c     = fd[b][0];
            const float left  = fd[b][1];
            const float right = fd[b][2];
            const float below = fd[b][3];
            const float above = fd[b][4];
            const float back  = fd[b][5];
            const float front = fd[b][6];

            const float gx_in  = (nx > 0.0f) ? (c - left)  : (right - c);
            const float gx_out = (nx > 0.0f) ? (right - c) : (c - left);
            const float gy_in  = (ny > 0.0f) ? (c - below) : (above - c);
            const float gy_out = (ny > 0.0f) ? (above - c) : (c - below);
            const float gz_in  = (nz > 0.0f) ? (c - back)  : (front - c);
            const float gz_out = (nz > 0.0f) ? (front - c) : (c - back);

            const float nd_in  = (gx_in  * nx + gy_in  * ny + gz_in  * nz) * INV_DX;
            const float nd_out = (gx_out * nx + gy_out * ny + gz_out * nz) * INV_DX;

            const float t = E_IN * (nd_in + gc_nd) - E_OUT * nd_out;
            t2sum += t * t;
        }
        contrib = (float)BATCH * sg * sg + t2sum;
    }

    // wave 0 (chunks 0+1): lanes 0-31 hold contrib, lanes 32-63 hold 0
    if ((threadIdx.x >> 6) == 0) {
        float v = contrib;
        for (int off = 32; off > 0; off >>= 1)
            v += __shfl_down(v, off, 64);
        if (threadIdx.x == 0) {
            const float scale = 1.0f / ((float)BATCH * (float)nb);
            atomicAdd(out, v * scale);
        }
    }
}

extern "C" void kernel_launch(void* const* d_in, const int* in_sizes, int n_in,
                              void* d_out, int out_size, void* d_ws, size_t ws_size,
                              hipStream_t stream) {
    const float* output  = (const float*)d_in[0];
    const float* q       = (const float*)d_in[1];
    const float* xq      = (const float*)d_in[2];
    // d_in[3] = points — redundant, reconstructed from indices
    const int*   x_idx   = (const int*)d_in[4];
    const int*   y_idx   = (const int*)d_in[5];
    const int*   z_idx   = (const int*)d_in[6];
    const float* normals = (const float*)d_in[7];
    float* out = (float*)d_out;

    const int nb = in_sizes[4];

    hipMemsetAsync(out, 0, sizeof(float), stream);

    const int block = 256;                 // 32 points x 8 charge-chunks
    const int grid  = (nb + PT - 1) / PT;
    interface_boundary_loss_kernel<<<grid, block, 0, stream>>>(
        output, q, xq, x_idx, y_idx, z_idx, normals, out, nb);
}